// Round 3
// baseline (2478.349 us; speedup 1.0000x reference)
//
#include <hip/hip_runtime.h>

#define TT 1000
#define CC 3
#define HH 64
#define WW 64
#define HW 4096
#define CHW 12288
#define CHW4 3072            // CHW / 4
#define NCHUNK 50
#define CLEN 20              // NCHUNK*CLEN == TT
#define GRID 1024            // persistent blocks: 4 blocks/CU x 256 CUs
#define NCONV 2000           // conv work items (512 threads per t -> 2 items/t)
#define NSUM 600             // NCHUNK * 12 chunk-sum items
#define NSCAN 768            // 3072 columns / 4 waves per item

// bf16 <-> f32 helpers (bf16 = top 16 bits of f32; RNE on encode)
__device__ __forceinline__ float bf2f(unsigned short u) {
    return __uint_as_float(((unsigned)u) << 16);
}
__device__ __forceinline__ unsigned short f2bf(float f) {
    unsigned u = __float_as_uint(f);
    return (unsigned short)((u + 0x7FFFu + ((u >> 16) & 1u)) >> 16);
}

// ---- device-scope grid barrier (sense-reversing via generation counter) ----
// bar[0] = arrival counter, bar[1] = generation. All GRID blocks co-resident
// (guaranteed: 256 thr, 0 LDS, VGPR<=128 via __launch_bounds__(256,4) -> 4 blk/CU).
__device__ __forceinline__ void grid_barrier(int* bar) {
    __syncthreads();
    if (threadIdx.x == 0) {
        __threadfence();   // make prior global writes visible device-wide
        int g = __hip_atomic_load(bar + 1, __ATOMIC_ACQUIRE, __HIP_MEMORY_SCOPE_AGENT);
        int p = __hip_atomic_fetch_add(bar, 1, __ATOMIC_ACQ_REL, __HIP_MEMORY_SCOPE_AGENT);
        if (p == GRID - 1) {
            __hip_atomic_store(bar, 0, __ATOMIC_RELAXED, __HIP_MEMORY_SCOPE_AGENT);
            __hip_atomic_store(bar + 1, g + 1, __ATOMIC_RELEASE, __HIP_MEMORY_SCOPE_AGENT);
        } else {
            while (__hip_atomic_load(bar + 1, __ATOMIC_ACQUIRE, __HIP_MEMORY_SCOPE_AGENT) == g) {
                __builtin_amdgcn_s_sleep(8);
            }
        }
    }
    __syncthreads();
}

// ---- phase A: conv3x3 + temb + et_coeff scale -> A (bf16)  [round-0 body] ----
// item in [0, NCONV): thread = (t, 2-row pair, 4-col group); halo cols via shuffles.
__device__ __forceinline__ void conv_phase(int item, bool in_bf16, const void* xin_v,
                                           const float* cw, const float* temb,
                                           const int* tarr, const float* ec,
                                           unsigned short* A) {
    int idx = item * 256 + (int)threadIdx.x;
    int wi = idx & 15;
    int hp = (idx >> 4) & 31;
    int t  = idx >> 9;                          // uniform within item
    int h0 = hp * 2;
    int w0 = wi * 4;

    const float* xtf = (const float*)xin_v + (size_t)t * CHW;
    const unsigned short* xtb = (const unsigned short*)xin_v + (size_t)t * CHW;

    float acc[2][CC][4];
    #pragma unroll
    for (int o = 0; o < 2; ++o)
        #pragma unroll
        for (int co = 0; co < CC; ++co)
            #pragma unroll
            for (int k = 0; k < 4; ++k) acc[o][co][k] = 0.f;

    #pragma unroll
    for (int ch = 0; ch < CC; ++ch) {
        #pragma unroll
        for (int j = 0; j < 4; ++j) {           // input row h0-1+j
            int h = h0 - 1 + j;
            bool hv = (unsigned)h < (unsigned)HH;
            float4 M;
            if (in_bf16) {
                ushort4 u = make_ushort4(0, 0, 0, 0);
                if (hv) u = *(const ushort4*)(xtb + ch * HW + h * WW + w0);
                M = make_float4(bf2f(u.x), bf2f(u.y), bf2f(u.z), bf2f(u.w));
            } else {
                M = hv ? *(const float4*)(xtf + ch * HW + h * WW + w0)
                       : make_float4(0.f, 0.f, 0.f, 0.f);
            }
            float left  = __shfl_up(M.w, 1);    if (wi == 0)  left  = 0.f;
            float right = __shfl_down(M.x, 1);  if (wi == 15) right = 0.f;
            float win[6] = {left, M.x, M.y, M.z, M.w, right};
            #pragma unroll
            for (int o = 0; o < 2; ++o) {
                const int kh = j - o;           // input row = (h0+o) + kh - 1
                if (kh >= 0 && kh <= 2) {
                    #pragma unroll
                    for (int co = 0; co < CC; ++co) {
                        float wa = cw[((co * CC + ch) * 3 + kh) * 3 + 0];
                        float wb = cw[((co * CC + ch) * 3 + kh) * 3 + 1];
                        float wc = cw[((co * CC + ch) * 3 + kh) * 3 + 2];
                        #pragma unroll
                        for (int k = 0; k < 4; ++k)
                            acc[o][co][k] += win[k] * wa + win[k + 1] * wb + win[k + 2] * wc;
                    }
                }
            }
        }
    }

    float e = ec[t];
    int tr = tarr[t];
    #pragma unroll
    for (int o = 0; o < 2; ++o)
        #pragma unroll
        for (int co = 0; co < CC; ++co) {
            float b = temb[tr * CC + co];
            ushort4 v;
            v.x = f2bf(e * (acc[o][co][0] + b));
            v.y = f2bf(e * (acc[o][co][1] + b));
            v.z = f2bf(e * (acc[o][co][2] + b));
            v.w = f2bf(e * (acc[o][co][3] + b));
            *(ushort4*)(A + (size_t)t * CHW + co * HW + (h0 + o) * WW + w0) = v;
        }
}

// ---- phase B: chunk sums S[ch,pos] = sum of A over the chunk's 20 t's ----
__device__ __forceinline__ void chunk_sum_phase(int item, const unsigned short* A,
                                                float4* S) {
    int ch = item / 12;                         // uniform within item
    int pos4 = (item % 12) * 256 + (int)threadIdx.x;
    const unsigned short* p = A + (size_t)ch * CLEN * CHW + pos4 * 4;
    float4 acc = make_float4(0.f, 0.f, 0.f, 0.f);
    #pragma unroll
    for (int i = 0; i < CLEN; ++i) {
        ushort4 u = *(const ushort4*)(p + (size_t)i * CHW);
        acc.x += bf2f(u.x); acc.y += bf2f(u.y); acc.z += bf2f(u.z); acc.w += bf2f(u.w);
    }
    S[(size_t)ch * CHW4 + pos4] = acc;
}

// ---- phase C: in-place exclusive shfl-scan over the chunk axis (1 wave/column) ----
__device__ __forceinline__ void scan_phase(int item, float4* S) {
    int gid  = item * 256 + (int)threadIdx.x;
    int wid  = gid >> 6;                        // pos4 column, 0..3071
    int lane = (int)threadIdx.x & 63;
    int cc = lane;                              // NCHUNK=50 <= 64: single segment
    float4 v = make_float4(0.f, 0.f, 0.f, 0.f);
    if (cc < NCHUNK) v = S[(size_t)cc * CHW4 + wid];
    float4 incl = v;
    #pragma unroll
    for (int d = 1; d < 64; d <<= 1) {
        float tx = __shfl_up(incl.x, d), ty = __shfl_up(incl.y, d);
        float tz = __shfl_up(incl.z, d), tw = __shfl_up(incl.w, d);
        if (lane >= d) { incl.x += tx; incl.y += ty; incl.z += tz; incl.w += tw; }
    }
    float4 ex;
    ex.x = __shfl_up(incl.x, 1); ex.y = __shfl_up(incl.y, 1);
    ex.z = __shfl_up(incl.z, 1); ex.w = __shfl_up(incl.w, 1);
    if (lane == 0) ex = make_float4(0.f, 0.f, 0.f, 0.f);
    if (cc < NCHUNK) S[(size_t)cc * CHW4 + wid] = ex;
}

// ---- phase D: xt_next[t] = ar[t]*xT + epc[t]*(offset + local running sum) ----
__device__ __forceinline__ void final_phase(int item, bool out_bf16,
                                            const unsigned short* A, const float4* S,
                                            const float4* xT, const float* ar,
                                            const float* epc, void* out_v) {
    int ch = item / 12;                         // uniform within item
    int pos4 = (item % 12) * 256 + (int)threadIdx.x;
    float4 acc = S[(size_t)ch * CHW4 + pos4];
    float4 xv = xT[pos4];
    const unsigned short* p = A + (size_t)ch * CLEN * CHW + pos4 * 4;
    float4* qf = (float4*)out_v + (size_t)(ch * CLEN + 1) * CHW4 + pos4;
    unsigned short* qb = (unsigned short*)out_v + ((size_t)(ch * CLEN + 1) * CHW4 + pos4) * 4;
    #pragma unroll
    for (int i = 0; i < CLEN; ++i) {
        int t = ch * CLEN + i;                  // uniform -> s_load coeffs
        ushort4 u = *(const ushort4*)(p + (size_t)i * CHW);
        acc.x += bf2f(u.x); acc.y += bf2f(u.y); acc.z += bf2f(u.z); acc.w += bf2f(u.w);
        float a = ar[t], e = epc[t];
        float4 r = make_float4(a * xv.x + e * acc.x, a * xv.y + e * acc.y,
                               a * xv.z + e * acc.z, a * xv.w + e * acc.w);
        if (out_bf16) {
            ushort4 ub;
            ub.x = f2bf(r.x); ub.y = f2bf(r.y); ub.z = f2bf(r.z); ub.w = f2bf(r.w);
            *(ushort4*)(qb + (size_t)i * CHW) = ub;
        } else {
            qf[(size_t)i * CHW4] = r;
        }
    }
}

// ---- init: out[0] = xT (f32), X[0] = bf16(xT), zero barrier words ----
__global__ __launch_bounds__(256) void init_kernel(const float4* __restrict__ x,
                                                   float4* __restrict__ out,
                                                   unsigned short* __restrict__ X,
                                                   int* __restrict__ bar) {
    int i = blockIdx.x * 256 + threadIdx.x;
    if (i == 0) { bar[0] = 0; bar[1] = 0; }
    if (i < CHW4) {
        float4 v = x[i];
        out[i] = v;
        ushort4 u;
        u.x = f2bf(v.x); u.y = f2bf(v.y); u.z = f2bf(v.z); u.w = f2bf(v.w);
        *(ushort4*)(X + (size_t)i * 4) = u;
    }
}

// ---- persistent mega-kernel: all 3 iterations, 12 phases, 11 grid barriers ----
__global__ __launch_bounds__(256, 4) void mega_kernel(const float* __restrict__ x,
                                                      const int* __restrict__ tarr,
                                                      const float* __restrict__ ar,
                                                      const float* __restrict__ ec,
                                                      const float* __restrict__ epc,
                                                      const float* __restrict__ cw,
                                                      const float* __restrict__ temb,
                                                      float* __restrict__ out,
                                                      unsigned short* __restrict__ A,
                                                      float* __restrict__ S,
                                                      unsigned short* __restrict__ X,
                                                      int* __restrict__ bar) {
    int b = blockIdx.x;
    for (int iter = 0; iter < 3; ++iter) {
        const void* xin = (iter == 0) ? (const void*)x : (const void*)X;
        bool inb = (iter != 0);

        // phase A: conv (2000 items over 1024 blocks -> <=2 items each)
        for (int item = b; item < NCONV; item += GRID)
            conv_phase(item, inb, xin, cw, temb, tarr, ec, A);
        grid_barrier(bar);

        // phase B: chunk sums
        if (b < NSUM) chunk_sum_phase(b, A, (float4*)S);
        grid_barrier(bar);

        // phase C: exclusive scan of chunk sums
        if (b < NSCAN) scan_phase(b, (float4*)S);
        grid_barrier(bar);

        // phase D: state materialization (bf16 X for iters 0,1; f32 out for iter 2)
        bool outb = (iter != 2);
        void* dst = outb ? (void*)X : (void*)out;
        if (b < NSUM) final_phase(b, outb, A, (const float4*)S, (const float4*)x,
                                  ar, epc, dst);
        if (iter < 2) grid_barrier(bar);
    }
}

extern "C" void kernel_launch(void* const* d_in, const int* in_sizes, int n_in,
                              void* d_out, int out_size, void* d_ws, size_t ws_size,
                              hipStream_t stream) {
    const float* x    = (const float*)d_in[0];   // (T+1, C, H, W)
    const int*   tarr = (const int*)  d_in[1];   // (T,)
    const float* ar   = (const float*)d_in[2];   // (T,1,1,1)
    const float* ec   = (const float*)d_in[3];   // (T,1,1,1)
    const float* epc  = (const float*)d_in[4];   // (T,1,1,1)
    const float* cw   = (const float*)d_in[5];   // (C,C,3,3)
    const float* temb = (const float*)d_in[6];   // (T,C)
    float* out = (float*)d_out;                  // (T+1, C, H, W)

    unsigned short* A = (unsigned short*)d_ws;            // TT*CHW bf16 (24.6 MB)
    float* S = (float*)(A + (size_t)TT * CHW);            // NCHUNK*CHW f32 (2.46 MB)
    unsigned short* X = (unsigned short*)(S + (size_t)NCHUNK * CHW);  // (TT+1)*CHW bf16
    int* bar = (int*)(X + (size_t)(TT + 1) * CHW);        // 2 ints (barrier state)

    init_kernel<<<12, 256, 0, stream>>>((const float4*)x, (float4*)out, X, bar);
    mega_kernel<<<GRID, 256, 0, stream>>>(x, tarr, ar, ec, epc, cw, temb,
                                          out, A, S, X, bar);
}

// Round 4
// 213.014 us; speedup vs baseline: 11.6347x; 11.6347x over previous
//
#include <hip/hip_runtime.h>

#define TT 1000
#define CC 3
#define HH 64
#define WW 64
#define HW 4096
#define CHW 12288
#define CHW4 3072            // CHW / 4
#define NCHUNK 100
#define CLEN 10              // NCHUNK*CLEN == TT
#define NCONVB 2000          // conv blocks (512 threads per t -> 2 blocks/t)

// bf16 <-> f32 helpers (bf16 = top 16 bits of f32; RNE on encode)
__device__ __forceinline__ float bf2f(unsigned short u) {
    return __uint_as_float(((unsigned)u) << 16);
}
__device__ __forceinline__ unsigned short f2bf(float f) {
    unsigned u = __float_as_uint(f);
    return (unsigned short)((u + 0x7FFFu + ((u >> 16) & 1u)) >> 16);
}

// A[t,c,h,w] = bf16( et_coeff[t] * (conv3x3(xin[t])[c,h,w] + temb[tarr[t], c]) )
// thread = (t, 2-row pair, 4-col group); 3 output channels share all loads.
// Halo columns via wave shuffles. Input either f32 (iter 1) or bf16 state.
// COPY_TAIL: blocks [NCONVB, NCONVB+12) instead copy xT -> out[0] (f32) and X[0] (bf16).
template <bool IN_BF16, bool COPY_TAIL>
__global__ __launch_bounds__(256) void conv_kernel(const void* __restrict__ xin_v,
                                                   const float* __restrict__ cw,
                                                   const float* __restrict__ temb,
                                                   const int* __restrict__ tarr,
                                                   const float* __restrict__ ec,
                                                   unsigned short* __restrict__ A,
                                                   float* __restrict__ out0,
                                                   unsigned short* __restrict__ X0) {
    if (COPY_TAIL && blockIdx.x >= NCONVB) {
        int i = (blockIdx.x - NCONVB) * 256 + threadIdx.x;
        if (i < CHW4) {
            float4 v = ((const float4*)xin_v)[i];   // iter-1 input is x (f32); x[0] = xT
            ((float4*)out0)[i] = v;
            ushort4 u;
            u.x = f2bf(v.x); u.y = f2bf(v.y); u.z = f2bf(v.z); u.w = f2bf(v.w);
            *(ushort4*)(X0 + (size_t)i * 4) = u;
        }
        return;
    }

    int idx = blockIdx.x * 256 + threadIdx.x;   // TT*32*16 = 512000 exactly
    int wi = idx & 15;
    int hp = (idx >> 4) & 31;
    int t  = idx >> 9;                          // block-uniform (2 blocks/t)
    int h0 = hp * 2;
    int w0 = wi * 4;

    const float* xtf = (const float*)xin_v + (size_t)t * CHW;
    const unsigned short* xtb = (const unsigned short*)xin_v + (size_t)t * CHW;

    float acc[2][CC][4];
    #pragma unroll
    for (int o = 0; o < 2; ++o)
        #pragma unroll
        for (int co = 0; co < CC; ++co)
            #pragma unroll
            for (int k = 0; k < 4; ++k) acc[o][co][k] = 0.f;

    #pragma unroll
    for (int ch = 0; ch < CC; ++ch) {
        #pragma unroll
        for (int j = 0; j < 4; ++j) {           // input row h0-1+j
            int h = h0 - 1 + j;
            bool hv = (unsigned)h < (unsigned)HH;
            float4 M;
            if (IN_BF16) {
                ushort4 u = make_ushort4(0, 0, 0, 0);
                if (hv) u = *(const ushort4*)(xtb + ch * HW + h * WW + w0);
                M = make_float4(bf2f(u.x), bf2f(u.y), bf2f(u.z), bf2f(u.w));
            } else {
                M = hv ? *(const float4*)(xtf + ch * HW + h * WW + w0)
                       : make_float4(0.f, 0.f, 0.f, 0.f);
            }
            float left  = __shfl_up(M.w, 1);    if (wi == 0)  left  = 0.f;
            float right = __shfl_down(M.x, 1);  if (wi == 15) right = 0.f;
            float win[6] = {left, M.x, M.y, M.z, M.w, right};
            #pragma unroll
            for (int o = 0; o < 2; ++o) {
                const int kh = j - o;           // input row = (h0+o) + kh - 1
                if (kh >= 0 && kh <= 2) {
                    #pragma unroll
                    for (int co = 0; co < CC; ++co) {
                        float wa = cw[((co * CC + ch) * 3 + kh) * 3 + 0];
                        float wb = cw[((co * CC + ch) * 3 + kh) * 3 + 1];
                        float wc = cw[((co * CC + ch) * 3 + kh) * 3 + 2];
                        #pragma unroll
                        for (int k = 0; k < 4; ++k)
                            acc[o][co][k] += win[k] * wa + win[k + 1] * wb + win[k + 2] * wc;
                    }
                }
            }
        }
    }

    float e = ec[t];
    int tr = tarr[t];
    #pragma unroll
    for (int o = 0; o < 2; ++o)
        #pragma unroll
        for (int co = 0; co < CC; ++co) {
            float b = temb[tr * CC + co];
            ushort4 v;
            v.x = f2bf(e * (acc[o][co][0] + b));
            v.y = f2bf(e * (acc[o][co][1] + b));
            v.z = f2bf(e * (acc[o][co][2] + b));
            v.w = f2bf(e * (acc[o][co][3] + b));
            *(ushort4*)(A + (size_t)t * CHW + co * HW + (h0 + o) * WW + w0) = v;
        }
}

// S[ch,pos] = sum of A over the chunk's CLEN t's (f32 accumulate from bf16)
__global__ __launch_bounds__(256) void chunk_sum_kernel(const unsigned short* __restrict__ A,
                                                        float4* __restrict__ S) {
    int ch = blockIdx.x / 12;                   // block-uniform
    int pos4 = (blockIdx.x % 12) * 256 + threadIdx.x;
    const unsigned short* p = A + (size_t)ch * CLEN * CHW + pos4 * 4;
    float4 acc = make_float4(0.f, 0.f, 0.f, 0.f);
    #pragma unroll
    for (int i = 0; i < CLEN; ++i) {
        ushort4 u = *(const ushort4*)(p + (size_t)i * CHW);
        acc.x += bf2f(u.x); acc.y += bf2f(u.y); acc.z += bf2f(u.z); acc.w += bf2f(u.w);
    }
    S[(size_t)ch * CHW4 + pos4] = acc;
}

// Wave-parallel in-place exclusive scan over the chunk axis.
// One wave per float4 column (3072 columns = 3072 waves); shfl-scan 64/segment.
__global__ __launch_bounds__(256) void scan_kernel(float4* __restrict__ S) {
    int gid  = blockIdx.x * 256 + threadIdx.x;
    int wid  = gid >> 6;                        // pos4 column, 0..3071
    int lane = threadIdx.x & 63;
    float4 carry = make_float4(0.f, 0.f, 0.f, 0.f);
    #pragma unroll
    for (int seg = 0; seg < (NCHUNK + 63) / 64; ++seg) {
        int cc = seg * 64 + lane;
        float4 v = make_float4(0.f, 0.f, 0.f, 0.f);
        if (cc < NCHUNK) v = S[(size_t)cc * CHW4 + wid];
        float4 incl = v;
        #pragma unroll
        for (int d = 1; d < 64; d <<= 1) {
            float tx = __shfl_up(incl.x, d), ty = __shfl_up(incl.y, d);
            float tz = __shfl_up(incl.z, d), tw = __shfl_up(incl.w, d);
            if (lane >= d) { incl.x += tx; incl.y += ty; incl.z += tz; incl.w += tw; }
        }
        float4 ex;
        ex.x = __shfl_up(incl.x, 1); ex.y = __shfl_up(incl.y, 1);
        ex.z = __shfl_up(incl.z, 1); ex.w = __shfl_up(incl.w, 1);
        if (lane == 0) ex = make_float4(0.f, 0.f, 0.f, 0.f);
        if (cc < NCHUNK)
            S[(size_t)cc * CHW4 + wid] = make_float4(carry.x + ex.x, carry.y + ex.y,
                                                     carry.z + ex.z, carry.w + ex.w);
        carry.x += __shfl(incl.x, 63); carry.y += __shfl(incl.y, 63);
        carry.z += __shfl(incl.z, 63); carry.w += __shfl(incl.w, 63);
    }
}

// xt_next[t] = ar[t]*xT + epc[t]*(chunk_offset + local running sum)
// OUT_BF16: write bf16 state X_ws[t+1] (iters 1,2). Else f32 d_out[t+1] (iter 3).
template <bool OUT_BF16>
__global__ __launch_bounds__(256) void final_kernel(const unsigned short* __restrict__ A,
                                                    const float4* __restrict__ S,
                                                    const float4* __restrict__ xT,
                                                    const float* __restrict__ ar,
                                                    const float* __restrict__ epc,
                                                    void* __restrict__ out_v) {
    int ch = blockIdx.x / 12;                   // block-uniform
    int pos4 = (blockIdx.x % 12) * 256 + threadIdx.x;
    float4 acc = S[(size_t)ch * CHW4 + pos4];
    float4 xv = xT[pos4];
    const unsigned short* p = A + (size_t)ch * CLEN * CHW + pos4 * 4;
    float4* qf = (float4*)out_v + (size_t)(ch * CLEN + 1) * CHW4 + pos4;
    unsigned short* qb = (unsigned short*)out_v + ((size_t)(ch * CLEN + 1) * CHW4 + pos4) * 4;
    #pragma unroll
    for (int i = 0; i < CLEN; ++i) {
        int t = ch * CLEN + i;                  // block-uniform -> s_load
        ushort4 u = *(const ushort4*)(p + (size_t)i * CHW);
        acc.x += bf2f(u.x); acc.y += bf2f(u.y); acc.z += bf2f(u.z); acc.w += bf2f(u.w);
        float a = ar[t], e = epc[t];
        float4 r = make_float4(a * xv.x + e * acc.x, a * xv.y + e * acc.y,
                               a * xv.z + e * acc.z, a * xv.w + e * acc.w);
        if (OUT_BF16) {
            ushort4 ub;
            ub.x = f2bf(r.x); ub.y = f2bf(r.y); ub.z = f2bf(r.z); ub.w = f2bf(r.w);
            *(ushort4*)(qb + (size_t)i * CHW) = ub;
        } else {
            qf[(size_t)i * CHW4] = r;
        }
    }
}

extern "C" void kernel_launch(void* const* d_in, const int* in_sizes, int n_in,
                              void* d_out, int out_size, void* d_ws, size_t ws_size,
                              hipStream_t stream) {
    const float* x    = (const float*)d_in[0];   // (T+1, C, H, W)
    const int*   tarr = (const int*)  d_in[1];   // (T,)
    const float* ar   = (const float*)d_in[2];   // (T,1,1,1)
    const float* ec   = (const float*)d_in[3];   // (T,1,1,1)
    const float* epc  = (const float*)d_in[4];   // (T,1,1,1)
    const float* cw   = (const float*)d_in[5];   // (C,C,3,3)
    const float* temb = (const float*)d_in[6];   // (T,C)
    float* out = (float*)d_out;                  // (T+1, C, H, W)

    unsigned short* A = (unsigned short*)d_ws;      // TT*CHW bf16 (24.6 MB)
    float* S = (float*)(A + (size_t)TT * CHW);      // NCHUNK*CHW f32 (4.9 MB)
    unsigned short* X = (unsigned short*)(S + (size_t)NCHUNK * CHW);  // (TT+1)*CHW bf16 state

    // iter 1: f32 x in -> bf16 X state out; tail blocks copy out[0]=xT, X[0]=bf16(xT)
    conv_kernel<false, true><<<NCONVB + 12, 256, 0, stream>>>(x, cw, temb, tarr, ec, A, out, X);
    chunk_sum_kernel<<<NCHUNK * 12, 256, 0, stream>>>(A, (float4*)S);
    scan_kernel<<<768, 256, 0, stream>>>((float4*)S);
    final_kernel<true><<<NCHUNK * 12, 256, 0, stream>>>(A, (const float4*)S,
                                                        (const float4*)x, ar, epc, X);

    // iter 2: bf16 X in -> bf16 X out
    conv_kernel<true, false><<<NCONVB, 256, 0, stream>>>(X, cw, temb, tarr, ec, A, out, X);
    chunk_sum_kernel<<<NCHUNK * 12, 256, 0, stream>>>(A, (float4*)S);
    scan_kernel<<<768, 256, 0, stream>>>((float4*)S);
    final_kernel<true><<<NCHUNK * 12, 256, 0, stream>>>(A, (const float4*)S,
                                                        (const float4*)x, ar, epc, X);

    // iter 3: bf16 X in -> f32 d_out
    conv_kernel<true, false><<<NCONVB, 256, 0, stream>>>(X, cw, temb, tarr, ec, A, out, X);
    chunk_sum_kernel<<<NCHUNK * 12, 256, 0, stream>>>(A, (float4*)S);
    scan_kernel<<<768, 256, 0, stream>>>((float4*)S);
    final_kernel<false><<<NCHUNK * 12, 256, 0, stream>>>(A, (const float4*)S,
                                                         (const float4*)x, ar, epc, out);
}

// Round 5
// 202.340 us; speedup vs baseline: 12.2484x; 1.0528x over previous
//
#include <hip/hip_runtime.h>

#define TT 1000
#define CC 3
#define HH 64
#define WW 64
#define HW 4096
#define CHW 12288
#define CHW4 3072            // CHW / 4
#define NCHUNK 50
#define CLEN 20              // NCHUNK*CLEN == TT
#define NCONVB 2000          // conv blocks (512 threads per t -> 2 blocks/t)

// bf16 <-> f32 helpers (bf16 = top 16 bits of f32; RNE on encode)
__device__ __forceinline__ float bf2f(unsigned short u) {
    return __uint_as_float(((unsigned)u) << 16);
}
__device__ __forceinline__ unsigned short f2bf(float f) {
    unsigned u = __float_as_uint(f);
    return (unsigned short)((u + 0x7FFFu + ((u >> 16) & 1u)) >> 16);
}

// A[t,c,h,w] = bf16( et_coeff[t] * (conv3x3(xin[t])[c,h,w] + temb[tarr[t], c]) )
// thread = (t, 2-row pair, 4-col group); 3 output channels share all loads.
// Halo columns via wave shuffles. Input either f32 (iter 1) or bf16 state.
// COPY_TAIL: blocks [NCONVB, NCONVB+12) instead copy xT -> out[0] (f32) and X[0] (bf16).
template <bool IN_BF16, bool COPY_TAIL>
__global__ __launch_bounds__(256) void conv_kernel(const void* __restrict__ xin_v,
                                                   const float* __restrict__ cw,
                                                   const float* __restrict__ temb,
                                                   const int* __restrict__ tarr,
                                                   const float* __restrict__ ec,
                                                   unsigned short* __restrict__ A,
                                                   float* __restrict__ out0,
                                                   unsigned short* __restrict__ X0) {
    if (COPY_TAIL && blockIdx.x >= NCONVB) {
        int i = (blockIdx.x - NCONVB) * 256 + threadIdx.x;
        if (i < CHW4) {
            float4 v = ((const float4*)xin_v)[i];   // iter-1 input is x (f32); x[0] = xT
            ((float4*)out0)[i] = v;
            ushort4 u;
            u.x = f2bf(v.x); u.y = f2bf(v.y); u.z = f2bf(v.z); u.w = f2bf(v.w);
            *(ushort4*)(X0 + (size_t)i * 4) = u;
        }
        return;
    }

    int idx = blockIdx.x * 256 + threadIdx.x;   // TT*32*16 = 512000 exactly
    int wi = idx & 15;
    int hp = (idx >> 4) & 31;
    int t  = idx >> 9;                          // block-uniform (2 blocks/t)
    int h0 = hp * 2;
    int w0 = wi * 4;

    const float* xtf = (const float*)xin_v + (size_t)t * CHW;
    const unsigned short* xtb = (const unsigned short*)xin_v + (size_t)t * CHW;

    float acc[2][CC][4];
    #pragma unroll
    for (int o = 0; o < 2; ++o)
        #pragma unroll
        for (int co = 0; co < CC; ++co)
            #pragma unroll
            for (int k = 0; k < 4; ++k) acc[o][co][k] = 0.f;

    #pragma unroll
    for (int ch = 0; ch < CC; ++ch) {
        #pragma unroll
        for (int j = 0; j < 4; ++j) {           // input row h0-1+j
            int h = h0 - 1 + j;
            bool hv = (unsigned)h < (unsigned)HH;
            float4 M;
            if (IN_BF16) {
                ushort4 u = make_ushort4(0, 0, 0, 0);
                if (hv) u = *(const ushort4*)(xtb + ch * HW + h * WW + w0);
                M = make_float4(bf2f(u.x), bf2f(u.y), bf2f(u.z), bf2f(u.w));
            } else {
                M = hv ? *(const float4*)(xtf + ch * HW + h * WW + w0)
                       : make_float4(0.f, 0.f, 0.f, 0.f);
            }
            float left  = __shfl_up(M.w, 1);    if (wi == 0)  left  = 0.f;
            float right = __shfl_down(M.x, 1);  if (wi == 15) right = 0.f;
            float win[6] = {left, M.x, M.y, M.z, M.w, right};
            #pragma unroll
            for (int o = 0; o < 2; ++o) {
                const int kh = j - o;           // input row = (h0+o) + kh - 1
                if (kh >= 0 && kh <= 2) {
                    #pragma unroll
                    for (int co = 0; co < CC; ++co) {
                        float wa = cw[((co * CC + ch) * 3 + kh) * 3 + 0];
                        float wb = cw[((co * CC + ch) * 3 + kh) * 3 + 1];
                        float wc = cw[((co * CC + ch) * 3 + kh) * 3 + 2];
                        #pragma unroll
                        for (int k = 0; k < 4; ++k)
                            acc[o][co][k] += win[k] * wa + win[k + 1] * wb + win[k + 2] * wc;
                    }
                }
            }
        }
    }

    float e = ec[t];
    int tr = tarr[t];
    #pragma unroll
    for (int o = 0; o < 2; ++o)
        #pragma unroll
        for (int co = 0; co < CC; ++co) {
            float b = temb[tr * CC + co];
            ushort4 v;
            v.x = f2bf(e * (acc[o][co][0] + b));
            v.y = f2bf(e * (acc[o][co][1] + b));
            v.z = f2bf(e * (acc[o][co][2] + b));
            v.w = f2bf(e * (acc[o][co][3] + b));
            *(ushort4*)(A + (size_t)t * CHW + co * HW + (h0 + o) * WW + w0) = v;
        }
}

// S[ch,pos] = sum of A over the chunk's CLEN t's (f32 accumulate from bf16)
__global__ __launch_bounds__(256) void chunk_sum_kernel(const unsigned short* __restrict__ A,
                                                        float4* __restrict__ S) {
    int ch = blockIdx.x / 12;                   // block-uniform
    int pos4 = (blockIdx.x % 12) * 256 + threadIdx.x;
    const unsigned short* p = A + (size_t)ch * CLEN * CHW + pos4 * 4;
    float4 acc = make_float4(0.f, 0.f, 0.f, 0.f);
    #pragma unroll
    for (int i = 0; i < CLEN; ++i) {
        ushort4 u = *(const ushort4*)(p + (size_t)i * CHW);
        acc.x += bf2f(u.x); acc.y += bf2f(u.y); acc.z += bf2f(u.z); acc.w += bf2f(u.w);
    }
    S[(size_t)ch * CHW4 + pos4] = acc;
}

// xt_next[t] = ar[t]*xT + epc[t]*(inline chunk-offset + local running sum)
// The exclusive chunk offset is computed inline: sum of S[j][pos4] for j < ch
// (column-local, coalesced, L2-resident) -- this removes the scan dispatch.
// OUT_BF16: write bf16 state X_ws[t+1] (iters 1,2). Else f32 d_out[t+1] (iter 3).
template <bool OUT_BF16>
__global__ __launch_bounds__(256) void final_kernel(const unsigned short* __restrict__ A,
                                                    const float4* __restrict__ S,
                                                    const float4* __restrict__ xT,
                                                    const float* __restrict__ ar,
                                                    const float* __restrict__ epc,
                                                    void* __restrict__ out_v) {
    int ch = blockIdx.x / 12;                   // block-uniform
    int pos4 = (blockIdx.x % 12) * 256 + threadIdx.x;

    // inline exclusive prefix over chunk sums (4 independent partials for ILP)
    float4 a0 = make_float4(0.f, 0.f, 0.f, 0.f);
    float4 a1 = make_float4(0.f, 0.f, 0.f, 0.f);
    float4 a2 = make_float4(0.f, 0.f, 0.f, 0.f);
    float4 a3 = make_float4(0.f, 0.f, 0.f, 0.f);
    int j = 0;
    for (; j + 4 <= ch; j += 4) {               // block-uniform trip count
        float4 v0 = S[(size_t)(j + 0) * CHW4 + pos4];
        float4 v1 = S[(size_t)(j + 1) * CHW4 + pos4];
        float4 v2 = S[(size_t)(j + 2) * CHW4 + pos4];
        float4 v3 = S[(size_t)(j + 3) * CHW4 + pos4];
        a0.x += v0.x; a0.y += v0.y; a0.z += v0.z; a0.w += v0.w;
        a1.x += v1.x; a1.y += v1.y; a1.z += v1.z; a1.w += v1.w;
        a2.x += v2.x; a2.y += v2.y; a2.z += v2.z; a2.w += v2.w;
        a3.x += v3.x; a3.y += v3.y; a3.z += v3.z; a3.w += v3.w;
    }
    for (; j < ch; ++j) {
        float4 v = S[(size_t)j * CHW4 + pos4];
        a0.x += v.x; a0.y += v.y; a0.z += v.z; a0.w += v.w;
    }
    float4 acc = make_float4((a0.x + a1.x) + (a2.x + a3.x),
                             (a0.y + a1.y) + (a2.y + a3.y),
                             (a0.z + a1.z) + (a2.z + a3.z),
                             (a0.w + a1.w) + (a2.w + a3.w));

    float4 xv = xT[pos4];
    const unsigned short* p = A + (size_t)ch * CLEN * CHW + pos4 * 4;
    float4* qf = (float4*)out_v + (size_t)(ch * CLEN + 1) * CHW4 + pos4;
    unsigned short* qb = (unsigned short*)out_v + ((size_t)(ch * CLEN + 1) * CHW4 + pos4) * 4;
    #pragma unroll
    for (int i = 0; i < CLEN; ++i) {
        int t = ch * CLEN + i;                  // block-uniform -> s_load
        ushort4 u = *(const ushort4*)(p + (size_t)i * CHW);
        acc.x += bf2f(u.x); acc.y += bf2f(u.y); acc.z += bf2f(u.z); acc.w += bf2f(u.w);
        float a = ar[t], e = epc[t];
        float4 r = make_float4(a * xv.x + e * acc.x, a * xv.y + e * acc.y,
                               a * xv.z + e * acc.z, a * xv.w + e * acc.w);
        if (OUT_BF16) {
            ushort4 ub;
            ub.x = f2bf(r.x); ub.y = f2bf(r.y); ub.z = f2bf(r.z); ub.w = f2bf(r.w);
            *(ushort4*)(qb + (size_t)i * CHW) = ub;
        } else {
            qf[(size_t)i * CHW4] = r;
        }
    }
}

extern "C" void kernel_launch(void* const* d_in, const int* in_sizes, int n_in,
                              void* d_out, int out_size, void* d_ws, size_t ws_size,
                              hipStream_t stream) {
    const float* x    = (const float*)d_in[0];   // (T+1, C, H, W)
    const int*   tarr = (const int*)  d_in[1];   // (T,)
    const float* ar   = (const float*)d_in[2];   // (T,1,1,1)
    const float* ec   = (const float*)d_in[3];   // (T,1,1,1)
    const float* epc  = (const float*)d_in[4];   // (T,1,1,1)
    const float* cw   = (const float*)d_in[5];   // (C,C,3,3)
    const float* temb = (const float*)d_in[6];   // (T,C)
    float* out = (float*)d_out;                  // (T+1, C, H, W)

    unsigned short* A = (unsigned short*)d_ws;      // TT*CHW bf16 (24.6 MB)
    float* S = (float*)(A + (size_t)TT * CHW);      // NCHUNK*CHW f32 (2.46 MB)
    unsigned short* X = (unsigned short*)(S + (size_t)NCHUNK * CHW);  // (TT+1)*CHW bf16 state

    // iter 1: f32 x in -> bf16 X state out; tail blocks copy out[0]=xT, X[0]=bf16(xT)
    conv_kernel<false, true><<<NCONVB + 12, 256, 0, stream>>>(x, cw, temb, tarr, ec, A, out, X);
    chunk_sum_kernel<<<NCHUNK * 12, 256, 0, stream>>>(A, (float4*)S);
    final_kernel<true><<<NCHUNK * 12, 256, 0, stream>>>(A, (const float4*)S,
                                                        (const float4*)x, ar, epc, X);

    // iter 2: bf16 X in -> bf16 X out
    conv_kernel<true, false><<<NCONVB, 256, 0, stream>>>(X, cw, temb, tarr, ec, A, out, X);
    chunk_sum_kernel<<<NCHUNK * 12, 256, 0, stream>>>(A, (float4*)S);
    final_kernel<true><<<NCHUNK * 12, 256, 0, stream>>>(A, (const float4*)S,
                                                        (const float4*)x, ar, epc, X);

    // iter 3: bf16 X in -> f32 d_out
    conv_kernel<true, false><<<NCONVB, 256, 0, stream>>>(X, cw, temb, tarr, ec, A, out, X);
    chunk_sum_kernel<<<NCHUNK * 12, 256, 0, stream>>>(A, (float4*)S);
    final_kernel<false><<<NCHUNK * 12, 256, 0, stream>>>(A, (const float4*)S,
                                                         (const float4*)x, ar, epc, out);
}